// Round 7
// baseline (351.212 us; speedup 1.0000x reference)
//
#include <hip/hip_runtime.h>
#include <math.h>

// MarginDevianceLoss: N=4096, D=256, K=8, targets = i/8.
// Outputs: [loss, prec, pos_d, neg_d] fp32.
//
// R7: - Triangle GEMM: sim is symmetric -> only blocks bx<=by compute (528 of
//       1024; lower blocks exit immediately). Upper blocks store both images
//       (normal store at j*4096+i, mirror scalar stores at i*4096+j); diagonal
//       blocks store once. MFMA work halved, store bytes unchanged (32 MB).
//     - Sweep absorbs finalize: per-block results atomically accumulated into
//       ws; last block (device-scope done-counter) writes d_out. 3 dispatches.
//     - Xf fragment-major bf16 layout (coalesced 1-KB fragment loads).

#define NROWS 4096
#define DIM   256
#define KCLS  8

typedef __bf16 bf16x8 __attribute__((ext_vector_type(8)));
typedef float  f32x4  __attribute__((ext_vector_type(4)));

__device__ __forceinline__ float softplus_fast(float z) {
    float m = fmaxf(z, 0.f);
    float e = __builtin_exp2f(-fabsf(z) * 1.4426950408889634f);
    return m + 0.6931471805599453f * __builtin_log2f(1.f + e);
}

__device__ __forceinline__ unsigned int pack_bf2(float a, float b) {
    unsigned int ua = __float_as_uint(a);
    unsigned int ub = __float_as_uint(b);
    ua = (ua + 0x7FFFu + ((ua >> 16) & 1u)) >> 16;   // RNE
    ub = (ub + 0x7FFFu + ((ub >> 16) & 1u)) >> 16;
    return ua | (ub << 16);
}

// X (fp32 row-major) -> Xf (bf16 fragment-major):
// Xf[((tile*8 + kf)*64 + lane)*8 + e] = X[tile*16 + (lane&15)][kf*32 + (lane>>4)*8 + e]
// Also zeroes the 8-float accumulator region (incl. done-counter).
__global__ __launch_bounds__(256)
void convert_kernel(const float* __restrict__ X, unsigned short* __restrict__ Xf,
                    float* __restrict__ accum)
{
    int v = blockIdx.x * 256 + threadIdx.x;    // 131072 fragment-slices of 16 B
    if (v < 8) accum[v] = 0.f;
    int tile = v >> 9;
    int kf   = (v >> 6) & 7;
    int lane = v & 63;
    int row  = tile * 16 + (lane & 15);
    int c4   = kf * 8 + (lane >> 4) * 2;       // col/4
    const float4* X4 = reinterpret_cast<const float4*>(X);
    float4 a = X4[row * 64 + c4];
    float4 b = X4[row * 64 + c4 + 1];
    uint4 o;
    o.x = pack_bf2(a.x, a.y);
    o.y = pack_bf2(a.z, a.w);
    o.z = pack_bf2(b.x, b.y);
    o.w = pack_bf2(b.z, b.w);
    reinterpret_cast<uint4*>(Xf)[v] = o;
}

// Grid (32,32); blocks with bx>by exit (triangle). Block: 4 waves; wave w ->
// i-tiles {bx*8+w*2, +1} (A cached in regs, K=256). All waves sweep j-tiles
// [by*8,+8) (B frags shared -> L1). Normal store at (j*4096+i); mirror store
// at (i*4096+j) for strictly-upper blocks.
__global__ __launch_bounds__(256)
void gemm_kernel(const unsigned short* __restrict__ Xf,
                 unsigned short* __restrict__ simB)
{
    if (blockIdx.x > blockIdx.y) return;           // uniform early-exit
    const bool mirror = (blockIdx.x < blockIdx.y);

    const int lane = threadIdx.x & 63;
    const int wave = threadIdx.x >> 6;
    const int quad = lane >> 4;
    const int n16  = lane & 15;
    const int it0  = blockIdx.x * 8 + wave * 2;    // first i-tile index
    const int i0   = it0 * 16;
    const int j0   = blockIdx.y * 128;
    const int jt0  = blockIdx.y * 8;

    // A fragments: 2 i-tiles x 8 k-frags, coalesced 1-KB loads
    bf16x8 afrag[2][8];
    #pragma unroll
    for (int t = 0; t < 2; ++t) {
        const unsigned short* ap = Xf + ((size_t)(it0 + t) * 8) * 512 + lane * 8;
        #pragma unroll
        for (int kf = 0; kf < 8; ++kf)
            afrag[t][kf] = *reinterpret_cast<const bf16x8*>(ap + kf * 512);
    }

    // normal store base (elements): (j0+n16)*4096 + i0 + quad*4
    unsigned short* sp0 = simB + (((size_t)(j0 + n16)) << 12) + i0 + quad * 4;

    bf16x8 bA[8], bB[8];
    auto loadB = [&](bf16x8* bf, int jt) {
        const unsigned short* bp = Xf + ((size_t)(jt0 + jt) * 8) * 512 + lane * 8;
        #pragma unroll
        for (int kf = 0; kf < 8; ++kf)
            bf[kf] = *reinterpret_cast<const bf16x8*>(bp + kf * 512);
    };
    auto tile = [&](const bf16x8* bf, int jt) {
        f32x4 ac[2] = {{0.f, 0.f, 0.f, 0.f}, {0.f, 0.f, 0.f, 0.f}};
        #pragma unroll
        for (int kf = 0; kf < 8; ++kf) {
            ac[0] = __builtin_amdgcn_mfma_f32_16x16x32_bf16(afrag[0][kf], bf[kf], ac[0], 0, 0, 0);
            ac[1] = __builtin_amdgcn_mfma_f32_16x16x32_bf16(afrag[1][kf], bf[kf], ac[1], 0, 0, 0);
        }
        const size_t joff = ((size_t)jt << 16);     // jt*16*4096 elements
        const int jcol = j0 + jt * 16 + n16;
        #pragma unroll
        for (int t = 0; t < 2; ++t) {
            uint2 pk;
            pk.x = pack_bf2(ac[t][0], ac[t][1]);
            pk.y = pack_bf2(ac[t][2], ac[t][3]);
            *reinterpret_cast<uint2*>(sp0 + joff + t * 16) = pk;
            if (mirror) {                          // uniform branch
                unsigned short* mp = simB + ((size_t)(i0 + t * 16 + quad * 4) << 12) + jcol;
                mp[0]         = (unsigned short)(pk.x & 0xffffu);
                mp[4096]      = (unsigned short)(pk.x >> 16);
                mp[2 * 4096]  = (unsigned short)(pk.y & 0xffffu);
                mp[3 * 4096]  = (unsigned short)(pk.y >> 16);
            }
        }
    };

    loadB(bA, 0);
    #pragma unroll 1
    for (int jp = 0; jp < 4; ++jp) {
        loadB(bB, 2 * jp + 1);
        tile(bA, 2 * jp);
        if (jp < 3) loadB(bA, 2 * jp + 2);
        tile(bB, 2 * jp + 1);
    }
}

// One block per row r. Row (8 KB bf16) -> 16 elems/thread in registers.
// Pass A: sum/sumsq + class-col extraction -> row stats in-block.
// Pass B: filter + softplus. Block result atomically added to accum;
// last block (done-counter) writes the 4 outputs.
__global__ __launch_bounds__(256)
void sweep_kernel(const unsigned short* __restrict__ simB,
                  float* __restrict__ accum,       // [0]=loss [1]=inv [2]=psum [3]=nsum [4]=counter
                  float* __restrict__ out)
{
    const int r = blockIdx.x;
    const int t = threadIdx.x;
    const int self = r & 7;
    const int rcls = r >> 3;

    const uint4* row = reinterpret_cast<const uint4*>(simB + ((size_t)r << 12));
    uint4 u0 = row[2 * t];
    uint4 u1 = row[2 * t + 1];
    unsigned int w[8] = {u0.x, u0.y, u0.z, u0.w, u1.x, u1.y, u1.z, u1.w};

    // ---- pass A: sum & sumsq over this thread's 16 elems ----
    float s1 = 0.f, s2 = 0.f;
    #pragma unroll
    for (int d = 0; d < 8; ++d) {
        float lo = __uint_as_float(w[d] << 16);
        float hi = __uint_as_float(w[d] & 0xffff0000u);
        s1 += lo + hi;
        s2 += lo * lo + hi * hi;
    }
    #pragma unroll
    for (int m = 1; m < 64; m <<= 1) {
        s1 += __shfl_xor(s1, m);
        s2 += __shfl_xor(s2, m);
    }
    __shared__ float sS1[4], sS2[4], clsLDS[KCLS];
    if ((t & 63) == 0) { sS1[t >> 6] = s1; sS2[t >> 6] = s2; }
    // class columns [rcls*8, rcls*8+8) live entirely in one thread's 16 elems
    const int towner = rcls >> 1;
    if (t == towner) {
        const int sub = (rcls & 1) * 4;
        #pragma unroll
        for (int d = 0; d < 4; ++d) {
            clsLDS[2 * d]     = __uint_as_float(w[sub + d] << 16);
            clsLDS[2 * d + 1] = __uint_as_float(w[sub + d] & 0xffff0000u);
        }
    }
    __syncthreads();
    const float S  = sS1[0] + sS1[1] + sS1[2] + sS1[3];
    const float SQ = sS2[0] + sS2[1] + sS2[2] + sS2[3];

    // ---- per-row stats (redundant per thread; LDS broadcasts) ----
    float cs[KCLS];
    #pragma unroll
    for (int m = 0; m < KCLS; ++m) cs[m] = clsLDS[m];
    float sii = cs[self];
    float psum = 0.f, psq = 0.f, pmin = 1e30f;
    #pragma unroll
    for (int m = 0; m < KCLS; ++m) {
        if (m != self) {
            psum += cs[m];
            psq  += cs[m] * cs[m];
            pmin  = fminf(pmin, cs[m]);
        }
    }
    const float p = (float)(KCLS - 1);            // 7
    const float mneg = (float)(NROWS - KCLS);     // 4088
    float nsum = S - psum - sii;
    float nsq  = SQ - psq - sii * sii;
    float pmean = psum / p;
    float pstd  = sqrtf(fmaxf(psq / p - pmean * pmean, 0.f));
    float nmean = nsum / mneg;
    float nstd  = sqrtf(fmaxf(nsq / mneg - nmean * nmean, 0.f));
    float inter  = 0.8f * (nstd * pmean + pstd * nmean) / (pstd + nstd) + 0.1f;
    float thresh = pmin - 0.05f;

    // ---- pass B: filter + softplus over this thread's 16 elems ----
    float cnt = 0.f, nls = 0.f;
    const int jb = t * 16;
    #pragma unroll
    for (int d = 0; d < 8; ++d) {
        float lo = __uint_as_float(w[d] << 16);
        float hi = __uint_as_float(w[d] & 0xffff0000u);
        int jl = jb + 2 * d;
        if (((jl >> 3) != rcls) && lo > thresh) {
            cnt += 1.f;
            nls += softplus_fast(40.f * (lo - inter));
        }
        if ((((jl + 1) >> 3) != rcls) && hi > thresh) {
            cnt += 1.f;
            nls += softplus_fast(40.f * (hi - inter));
        }
    }
    #pragma unroll
    for (int off = 32; off > 0; off >>= 1) {
        cnt += __shfl_down(cnt, off);
        nls += __shfl_down(nls, off);
    }
    __shared__ float sc[4], sn[4];
    if ((t & 63) == 0) { sc[t >> 6] = cnt; sn[t >> 6] = nls; }
    __syncthreads();
    if (t == 0) {
        float C = sc[0] + sc[1] + sc[2] + sc[3];
        float L = sn[0] + sn[1] + sn[2] + sn[3];
        int ci = (int)C;
        float pl = 0.f;
        #pragma unroll
        for (int m = 0; m < KCLS; ++m) {
            if (m != self) pl += softplus_fast(-10.f * (cs[m] - inter));
        }
        pl *= 0.2f / p;
        float rowLoss = (ci > 0) ? (pl + 0.05f * L / C) : 0.f;
        float rowInv  = (ci == 0) ? 1.f : 0.f;
        atomicAdd(&accum[0], rowLoss);
        atomicAdd(&accum[1], rowInv);
        atomicAdd(&accum[2], psum);
        atomicAdd(&accum[3], nsum);
        __threadfence();
        unsigned int done = __float_as_uint(1.f);  // (unused) keep simple:
        unsigned int old = atomicAdd((unsigned int*)&accum[4], 1u);
        if (old == NROWS - 1) {
            // last block: all prior atomics visible (device-scope)
            float Lt = atomicAdd(&accum[0], 0.f);
            float It = atomicAdd(&accum[1], 0.f);
            float Pt = atomicAdd(&accum[2], 0.f);
            float Nt = atomicAdd(&accum[3], 0.f);
            out[0] = Lt / (float)NROWS;
            out[1] = It / (float)NROWS;
            out[2] = Pt / ((float)NROWS * (float)(KCLS - 1));
            out[3] = Nt / ((float)NROWS * (float)(NROWS - KCLS));
        }
        (void)done;
    }
}

extern "C" void kernel_launch(void* const* d_in, const int* in_sizes, int n_in,
                              void* d_out, int out_size, void* d_ws, size_t ws_size,
                              hipStream_t stream)
{
    const float* X = (const float*)d_in[0];

    float* ws    = (float*)d_ws;
    float* accum = ws;                                        // 8 floats
    unsigned short* Xf   = (unsigned short*)(ws + 8);         // 2 MB
    unsigned short* simB = Xf + (size_t)NROWS * DIM;          // 32 MB
    // total ws use: ~34 MB

    convert_kernel<<<512, 256, 0, stream>>>(X, Xf, accum);

    dim3 grid(32, 32);   // triangle: bx>by blocks exit immediately
    gemm_kernel<<<grid, 256, 0, stream>>>(Xf, simB);

    sweep_kernel<<<NROWS, 256, 0, stream>>>(simB, accum, (float*)d_out);
}

// Round 8
// 108.159 us; speedup vs baseline: 3.2472x; 3.2472x over previous
//
#include <hip/hip_runtime.h>
#include <math.h>

// MarginDevianceLoss: N=4096, D=256, K=8, targets = i/8.
// Outputs: [loss, prec, pos_d, neg_d] fp32.
//
// R8 = R6 + triangle GEMM (from R7), WITHOUT R7's fused-finalize atomics.
//   R7 lesson: same-address device atomics cost ~13.5 ns each serialized;
//   4096 blocks x 5 atomics = 276 us. Never fuse the final reduction that way.
//  - Triangle GEMM: blocks bx>by exit; upper blocks store both images
//    (normal store at j*4096+i, mirror scalar stores at i*4096+j).
//  - Sweep: one block/row, row stats in-block, plain array stores.
//  - finalize: separate 1-block reduction. 4 dispatches, no atomics at all.

#define NROWS 4096
#define DIM   256
#define KCLS  8

typedef __bf16 bf16x8 __attribute__((ext_vector_type(8)));
typedef float  f32x4  __attribute__((ext_vector_type(4)));

__device__ __forceinline__ float softplus_fast(float z) {
    float m = fmaxf(z, 0.f);
    float e = __builtin_exp2f(-fabsf(z) * 1.4426950408889634f);
    return m + 0.6931471805599453f * __builtin_log2f(1.f + e);
}

__device__ __forceinline__ unsigned int pack_bf2(float a, float b) {
    unsigned int ua = __float_as_uint(a);
    unsigned int ub = __float_as_uint(b);
    ua = (ua + 0x7FFFu + ((ua >> 16) & 1u)) >> 16;   // RNE
    ub = (ub + 0x7FFFu + ((ub >> 16) & 1u)) >> 16;
    return ua | (ub << 16);
}

// X (fp32 row-major) -> Xf (bf16 fragment-major):
// Xf[((tile*8 + kf)*64 + lane)*8 + e] = X[tile*16 + (lane&15)][kf*32 + (lane>>4)*8 + e]
__global__ __launch_bounds__(256)
void convert_kernel(const float* __restrict__ X, unsigned short* __restrict__ Xf)
{
    int v = blockIdx.x * 256 + threadIdx.x;    // 131072 fragment-slices of 16 B
    int tile = v >> 9;
    int kf   = (v >> 6) & 7;
    int lane = v & 63;
    int row  = tile * 16 + (lane & 15);
    int c4   = kf * 8 + (lane >> 4) * 2;       // col/4
    const float4* X4 = reinterpret_cast<const float4*>(X);
    float4 a = X4[row * 64 + c4];
    float4 b = X4[row * 64 + c4 + 1];
    uint4 o;
    o.x = pack_bf2(a.x, a.y);
    o.y = pack_bf2(a.z, a.w);
    o.z = pack_bf2(b.x, b.y);
    o.w = pack_bf2(b.z, b.w);
    reinterpret_cast<uint4*>(Xf)[v] = o;
}

// Grid (32,32); blocks with bx>by exit (triangle). Block: 4 waves; wave w ->
// i-tiles {bx*8+w*2, +1} (A cached in regs, K=256). All waves sweep j-tiles
// [by*8,+8) (B frags shared -> L1). Normal store at (j*4096+i); mirror store
// at (i*4096+j) for strictly-upper blocks.
__global__ __launch_bounds__(256)
void gemm_kernel(const unsigned short* __restrict__ Xf,
                 unsigned short* __restrict__ simB)
{
    if (blockIdx.x > blockIdx.y) return;           // uniform early-exit
    const bool mirror = (blockIdx.x < blockIdx.y);

    const int lane = threadIdx.x & 63;
    const int wave = threadIdx.x >> 6;
    const int quad = lane >> 4;
    const int n16  = lane & 15;
    const int it0  = blockIdx.x * 8 + wave * 2;    // first i-tile index
    const int i0   = it0 * 16;
    const int j0   = blockIdx.y * 128;
    const int jt0  = blockIdx.y * 8;

    // A fragments: 2 i-tiles x 8 k-frags, coalesced 1-KB loads
    bf16x8 afrag[2][8];
    #pragma unroll
    for (int t = 0; t < 2; ++t) {
        const unsigned short* ap = Xf + ((size_t)(it0 + t) * 8) * 512 + lane * 8;
        #pragma unroll
        for (int kf = 0; kf < 8; ++kf)
            afrag[t][kf] = *reinterpret_cast<const bf16x8*>(ap + kf * 512);
    }

    // normal store base (elements): (j0+n16)*4096 + i0 + quad*4
    unsigned short* sp0 = simB + (((size_t)(j0 + n16)) << 12) + i0 + quad * 4;

    bf16x8 bA[8], bB[8];
    auto loadB = [&](bf16x8* bf, int jt) {
        const unsigned short* bp = Xf + ((size_t)(jt0 + jt) * 8) * 512 + lane * 8;
        #pragma unroll
        for (int kf = 0; kf < 8; ++kf)
            bf[kf] = *reinterpret_cast<const bf16x8*>(bp + kf * 512);
    };
    auto tile = [&](const bf16x8* bf, int jt) {
        f32x4 ac[2] = {{0.f, 0.f, 0.f, 0.f}, {0.f, 0.f, 0.f, 0.f}};
        #pragma unroll
        for (int kf = 0; kf < 8; ++kf) {
            ac[0] = __builtin_amdgcn_mfma_f32_16x16x32_bf16(afrag[0][kf], bf[kf], ac[0], 0, 0, 0);
            ac[1] = __builtin_amdgcn_mfma_f32_16x16x32_bf16(afrag[1][kf], bf[kf], ac[1], 0, 0, 0);
        }
        const size_t joff = ((size_t)jt << 16);     // jt*16*4096 elements
        const int jcol = j0 + jt * 16 + n16;
        #pragma unroll
        for (int t = 0; t < 2; ++t) {
            uint2 pk;
            pk.x = pack_bf2(ac[t][0], ac[t][1]);
            pk.y = pack_bf2(ac[t][2], ac[t][3]);
            *reinterpret_cast<uint2*>(sp0 + joff + t * 16) = pk;
            if (mirror) {                          // uniform branch
                unsigned short* mp = simB + ((size_t)(i0 + t * 16 + quad * 4) << 12) + jcol;
                mp[0]         = (unsigned short)(pk.x & 0xffffu);
                mp[4096]      = (unsigned short)(pk.x >> 16);
                mp[2 * 4096]  = (unsigned short)(pk.y & 0xffffu);
                mp[3 * 4096]  = (unsigned short)(pk.y >> 16);
            }
        }
    };

    loadB(bA, 0);
    #pragma unroll 1
    for (int jp = 0; jp < 4; ++jp) {
        loadB(bB, 2 * jp + 1);
        tile(bA, 2 * jp);
        if (jp < 3) loadB(bA, 2 * jp + 2);
        tile(bB, 2 * jp + 1);
    }
}

// One block per row r. Row (8 KB bf16) -> 16 elems/thread in registers.
// Pass A: sum/sumsq + class-col extraction -> row stats in-block.
// Pass B: filter + softplus. Plain array stores (NO atomics).
__global__ __launch_bounds__(256)
void sweep_kernel(const unsigned short* __restrict__ simB,
                  float* __restrict__ rowLoss,
                  int* __restrict__ rowCnt,
                  float* __restrict__ rowPsum,
                  float* __restrict__ rowNsum)
{
    const int r = blockIdx.x;
    const int t = threadIdx.x;
    const int self = r & 7;
    const int rcls = r >> 3;

    const uint4* row = reinterpret_cast<const uint4*>(simB + ((size_t)r << 12));
    uint4 u0 = row[2 * t];
    uint4 u1 = row[2 * t + 1];
    unsigned int w[8] = {u0.x, u0.y, u0.z, u0.w, u1.x, u1.y, u1.z, u1.w};

    // ---- pass A: sum & sumsq over this thread's 16 elems ----
    float s1 = 0.f, s2 = 0.f;
    #pragma unroll
    for (int d = 0; d < 8; ++d) {
        float lo = __uint_as_float(w[d] << 16);
        float hi = __uint_as_float(w[d] & 0xffff0000u);
        s1 += lo + hi;
        s2 += lo * lo + hi * hi;
    }
    #pragma unroll
    for (int m = 1; m < 64; m <<= 1) {
        s1 += __shfl_xor(s1, m);
        s2 += __shfl_xor(s2, m);
    }
    __shared__ float sS1[4], sS2[4], clsLDS[KCLS];
    if ((t & 63) == 0) { sS1[t >> 6] = s1; sS2[t >> 6] = s2; }
    // class columns [rcls*8, rcls*8+8) live entirely in one thread's 16 elems
    const int towner = rcls >> 1;
    if (t == towner) {
        const int sub = (rcls & 1) * 4;
        #pragma unroll
        for (int d = 0; d < 4; ++d) {
            clsLDS[2 * d]     = __uint_as_float(w[sub + d] << 16);
            clsLDS[2 * d + 1] = __uint_as_float(w[sub + d] & 0xffff0000u);
        }
    }
    __syncthreads();
    const float S  = sS1[0] + sS1[1] + sS1[2] + sS1[3];
    const float SQ = sS2[0] + sS2[1] + sS2[2] + sS2[3];

    // ---- per-row stats (redundant per thread; LDS broadcasts) ----
    float cs[KCLS];
    #pragma unroll
    for (int m = 0; m < KCLS; ++m) cs[m] = clsLDS[m];
    float sii = cs[self];
    float psum = 0.f, psq = 0.f, pmin = 1e30f;
    #pragma unroll
    for (int m = 0; m < KCLS; ++m) {
        if (m != self) {
            psum += cs[m];
            psq  += cs[m] * cs[m];
            pmin  = fminf(pmin, cs[m]);
        }
    }
    const float p = (float)(KCLS - 1);            // 7
    const float mneg = (float)(NROWS - KCLS);     // 4088
    float nsum = S - psum - sii;
    float nsq  = SQ - psq - sii * sii;
    float pmean = psum / p;
    float pstd  = sqrtf(fmaxf(psq / p - pmean * pmean, 0.f));
    float nmean = nsum / mneg;
    float nstd  = sqrtf(fmaxf(nsq / mneg - nmean * nmean, 0.f));
    float inter  = 0.8f * (nstd * pmean + pstd * nmean) / (pstd + nstd) + 0.1f;
    float thresh = pmin - 0.05f;

    // ---- pass B: filter + softplus over this thread's 16 elems ----
    float cnt = 0.f, nls = 0.f;
    const int jb = t * 16;
    #pragma unroll
    for (int d = 0; d < 8; ++d) {
        float lo = __uint_as_float(w[d] << 16);
        float hi = __uint_as_float(w[d] & 0xffff0000u);
        int jl = jb + 2 * d;
        if (((jl >> 3) != rcls) && lo > thresh) {
            cnt += 1.f;
            nls += softplus_fast(40.f * (lo - inter));
        }
        if ((((jl + 1) >> 3) != rcls) && hi > thresh) {
            cnt += 1.f;
            nls += softplus_fast(40.f * (hi - inter));
        }
    }
    #pragma unroll
    for (int off = 32; off > 0; off >>= 1) {
        cnt += __shfl_down(cnt, off);
        nls += __shfl_down(nls, off);
    }
    __shared__ float sc[4], sn[4];
    if ((t & 63) == 0) { sc[t >> 6] = cnt; sn[t >> 6] = nls; }
    __syncthreads();
    if (t == 0) {
        float C = sc[0] + sc[1] + sc[2] + sc[3];
        float L = sn[0] + sn[1] + sn[2] + sn[3];
        int ci = (int)C;
        float pl = 0.f;
        #pragma unroll
        for (int m = 0; m < KCLS; ++m) {
            if (m != self) pl += softplus_fast(-10.f * (cs[m] - inter));
        }
        pl *= 0.2f / p;
        rowCnt[r]  = ci;
        rowPsum[r] = psum;
        rowNsum[r] = nsum;
        rowLoss[r] = (ci > 0) ? (pl + 0.05f * L / C) : 0.f;
    }
}

__global__ __launch_bounds__(256)
void finalize_kernel(const float* __restrict__ rowLoss,
                     const int* __restrict__ rowCnt,
                     const float* __restrict__ rowPsum,
                     const float* __restrict__ rowNsum,
                     float* __restrict__ out)
{
    const int t = threadIdx.x;
    float loss = 0.f, inv = 0.f, pd = 0.f, nd = 0.f;
    for (int r = t; r < NROWS; r += 256) {
        loss += rowLoss[r];
        inv  += (rowCnt[r] == 0) ? 1.f : 0.f;
        pd   += rowPsum[r];
        nd   += rowNsum[r];
    }
    #pragma unroll
    for (int off = 32; off > 0; off >>= 1) {
        loss += __shfl_down(loss, off);
        inv  += __shfl_down(inv, off);
        pd   += __shfl_down(pd, off);
        nd   += __shfl_down(nd, off);
    }
    __shared__ float sl[4], si[4], sp[4], sq[4];
    int w = t >> 6;
    if ((t & 63) == 0) { sl[w] = loss; si[w] = inv; sp[w] = pd; sq[w] = nd; }
    __syncthreads();
    if (t == 0) {
        float L = sl[0] + sl[1] + sl[2] + sl[3];
        float I = si[0] + si[1] + si[2] + si[3];
        float P = sp[0] + sp[1] + sp[2] + sp[3];
        float Nn = sq[0] + sq[1] + sq[2] + sq[3];
        out[0] = L / (float)NROWS;
        out[1] = I / (float)NROWS;
        out[2] = P / ((float)NROWS * (float)(KCLS - 1));
        out[3] = Nn / ((float)NROWS * (float)(NROWS - KCLS));
    }
}

extern "C" void kernel_launch(void* const* d_in, const int* in_sizes, int n_in,
                              void* d_out, int out_size, void* d_ws, size_t ws_size,
                              hipStream_t stream)
{
    const float* X = (const float*)d_in[0];

    float* ws      = (float*)d_ws;
    float* rowLoss = ws;                           // 4096
    float* rowPsum = ws + NROWS;                   // 4096
    float* rowNsum = ws + 2 * NROWS;               // 4096
    int*   rowCnt  = (int*)(ws + 3 * NROWS);       // 4096
    unsigned short* Xf   = (unsigned short*)(ws + 4 * NROWS);   // 2 MB
    unsigned short* simB = Xf + (size_t)NROWS * DIM;            // 32 MB
    // total ws use: ~34.1 MB; no zero-init required (no atomics anywhere)

    convert_kernel<<<512, 256, 0, stream>>>(X, Xf);

    dim3 grid(32, 32);   // triangle: bx>by blocks exit immediately
    gemm_kernel<<<grid, 256, 0, stream>>>(Xf, simB);

    sweep_kernel<<<NROWS, 256, 0, stream>>>(simB, rowLoss, rowCnt, rowPsum, rowNsum);

    finalize_kernel<<<1, 256, 0, stream>>>(rowLoss, rowCnt, rowPsum, rowNsum,
                                           (float*)d_out);
}

// Round 9
// 105.374 us; speedup vs baseline: 3.3330x; 1.0264x over previous
//
#include <hip/hip_runtime.h>
#include <math.h>

// MarginDevianceLoss: N=4096, D=256, K=8, targets = i/8.
// Outputs: [loss, prec, pos_d, neg_d] fp32.
//
// R9: - sim row PITCH padded 4096 -> 4128 elements (8256 B): the R6/R8 store
//       pattern wrote 16 rows exactly 8 KB apart per instruction (power-of-2
//       stride) -> L2 channel hotspot, ~1.2 TB/s effective store BW (why the
//       triangle GEMM was neutral: stores, not MFMA, bound the kernel).
//     - full GEMM again (no triangle/mirror), grid (32,64): 2048 blocks of
//       64-col j-slices -> 2x waves in flight, smaller tail.
//     - Xf fragment-major bf16 layout (coalesced 1-KB fragment loads).
//     - sweep: one block/row, stats in-block, plain stores; finalize separate.

#define NROWS 4096
#define DIM   256
#define KCLS  8
#define PITCH 4128   // sim row pitch in elements (8256 B; 16-B aligned, not 8-KB)

typedef __bf16 bf16x8 __attribute__((ext_vector_type(8)));
typedef float  f32x4  __attribute__((ext_vector_type(4)));

__device__ __forceinline__ float softplus_fast(float z) {
    float m = fmaxf(z, 0.f);
    float e = __builtin_exp2f(-fabsf(z) * 1.4426950408889634f);
    return m + 0.6931471805599453f * __builtin_log2f(1.f + e);
}

__device__ __forceinline__ unsigned int pack_bf2(float a, float b) {
    unsigned int ua = __float_as_uint(a);
    unsigned int ub = __float_as_uint(b);
    ua = (ua + 0x7FFFu + ((ua >> 16) & 1u)) >> 16;   // RNE
    ub = (ub + 0x7FFFu + ((ub >> 16) & 1u)) >> 16;
    return ua | (ub << 16);
}

// X (fp32 row-major) -> Xf (bf16 fragment-major):
// Xf[((tile*8 + kf)*64 + lane)*8 + e] = X[tile*16 + (lane&15)][kf*32 + (lane>>4)*8 + e]
__global__ __launch_bounds__(256)
void convert_kernel(const float* __restrict__ X, unsigned short* __restrict__ Xf)
{
    int v = blockIdx.x * 256 + threadIdx.x;    // 131072 fragment-slices of 16 B
    int tile = v >> 9;
    int kf   = (v >> 6) & 7;
    int lane = v & 63;
    int row  = tile * 16 + (lane & 15);
    int c4   = kf * 8 + (lane >> 4) * 2;       // col/4
    const float4* X4 = reinterpret_cast<const float4*>(X);
    float4 a = X4[row * 64 + c4];
    float4 b = X4[row * 64 + c4 + 1];
    uint4 o;
    o.x = pack_bf2(a.x, a.y);
    o.y = pack_bf2(a.z, a.w);
    o.z = pack_bf2(b.x, b.y);
    o.w = pack_bf2(b.z, b.w);
    reinterpret_cast<uint4*>(Xf)[v] = o;
}

// Grid (32,64). Block: 4 waves; wave w -> i-tiles {bx*8+w*2, +1} (A cached in
// regs, K=256). All waves sweep j-tiles [by*4, +4) (B frags shared -> L1).
// Stores sim bf16 at (j*PITCH + i)  [row-major by symmetry].
__global__ __launch_bounds__(256)
void gemm_kernel(const unsigned short* __restrict__ Xf,
                 unsigned short* __restrict__ simB)
{
    const int lane = threadIdx.x & 63;
    const int wave = threadIdx.x >> 6;
    const int quad = lane >> 4;
    const int n16  = lane & 15;
    const int it0  = blockIdx.x * 8 + wave * 2;    // first i-tile index
    const int i0   = it0 * 16;
    const int j0   = blockIdx.y * 64;
    const int jt0  = blockIdx.y * 4;

    // A fragments: 2 i-tiles x 8 k-frags, coalesced 1-KB loads
    bf16x8 afrag[2][8];
    #pragma unroll
    for (int t = 0; t < 2; ++t) {
        const unsigned short* ap = Xf + ((size_t)(it0 + t) * 8) * 512 + lane * 8;
        #pragma unroll
        for (int kf = 0; kf < 8; ++kf)
            afrag[t][kf] = *reinterpret_cast<const bf16x8*>(ap + kf * 512);
    }

    // store base (elements): (j0+n16)*PITCH + i0 + quad*4
    unsigned short* sp0 = simB + (size_t)(j0 + n16) * PITCH + i0 + quad * 4;

    bf16x8 bA[8], bB[8];
    auto loadB = [&](bf16x8* bf, int jt) {
        const unsigned short* bp = Xf + ((size_t)(jt0 + jt) * 8) * 512 + lane * 8;
        #pragma unroll
        for (int kf = 0; kf < 8; ++kf)
            bf[kf] = *reinterpret_cast<const bf16x8*>(bp + kf * 512);
    };
    auto tile = [&](const bf16x8* bf, int jt) {
        f32x4 ac[2] = {{0.f, 0.f, 0.f, 0.f}, {0.f, 0.f, 0.f, 0.f}};
        #pragma unroll
        for (int kf = 0; kf < 8; ++kf) {
            ac[0] = __builtin_amdgcn_mfma_f32_16x16x32_bf16(afrag[0][kf], bf[kf], ac[0], 0, 0, 0);
            ac[1] = __builtin_amdgcn_mfma_f32_16x16x32_bf16(afrag[1][kf], bf[kf], ac[1], 0, 0, 0);
        }
        const size_t joff = (size_t)jt * 16 * PITCH;
        #pragma unroll
        for (int t = 0; t < 2; ++t) {
            uint2 pk;
            pk.x = pack_bf2(ac[t][0], ac[t][1]);
            pk.y = pack_bf2(ac[t][2], ac[t][3]);
            *reinterpret_cast<uint2*>(sp0 + joff + t * 16) = pk;
        }
    };

    loadB(bA, 0);
    #pragma unroll 1
    for (int jp = 0; jp < 2; ++jp) {
        loadB(bB, 2 * jp + 1);
        tile(bA, 2 * jp);
        if (jp < 1) loadB(bA, 2 * jp + 2);
        tile(bB, 2 * jp + 1);
    }
}

// One block per row r. Row (8 KB bf16 at pitch PITCH) -> 16 elems/thread.
// Pass A: sum/sumsq + class-col extraction -> row stats in-block.
// Pass B: filter + softplus. Plain array stores (NO atomics).
__global__ __launch_bounds__(256)
void sweep_kernel(const unsigned short* __restrict__ simB,
                  float* __restrict__ rowLoss,
                  int* __restrict__ rowCnt,
                  float* __restrict__ rowPsum,
                  float* __restrict__ rowNsum)
{
    const int r = blockIdx.x;
    const int t = threadIdx.x;
    const int self = r & 7;
    const int rcls = r >> 3;

    const uint4* row = reinterpret_cast<const uint4*>(simB + (size_t)r * PITCH);
    uint4 u0 = row[2 * t];
    uint4 u1 = row[2 * t + 1];
    unsigned int w[8] = {u0.x, u0.y, u0.z, u0.w, u1.x, u1.y, u1.z, u1.w};

    // ---- pass A: sum & sumsq over this thread's 16 elems ----
    float s1 = 0.f, s2 = 0.f;
    #pragma unroll
    for (int d = 0; d < 8; ++d) {
        float lo = __uint_as_float(w[d] << 16);
        float hi = __uint_as_float(w[d] & 0xffff0000u);
        s1 += lo + hi;
        s2 += lo * lo + hi * hi;
    }
    #pragma unroll
    for (int m = 1; m < 64; m <<= 1) {
        s1 += __shfl_xor(s1, m);
        s2 += __shfl_xor(s2, m);
    }
    __shared__ float sS1[4], sS2[4], clsLDS[KCLS];
    if ((t & 63) == 0) { sS1[t >> 6] = s1; sS2[t >> 6] = s2; }
    // class columns [rcls*8, rcls*8+8) live entirely in one thread's 16 elems
    const int towner = rcls >> 1;
    if (t == towner) {
        const int sub = (rcls & 1) * 4;
        #pragma unroll
        for (int d = 0; d < 4; ++d) {
            clsLDS[2 * d]     = __uint_as_float(w[sub + d] << 16);
            clsLDS[2 * d + 1] = __uint_as_float(w[sub + d] & 0xffff0000u);
        }
    }
    __syncthreads();
    const float S  = sS1[0] + sS1[1] + sS1[2] + sS1[3];
    const float SQ = sS2[0] + sS2[1] + sS2[2] + sS2[3];

    // ---- per-row stats (redundant per thread; LDS broadcasts) ----
    float cs[KCLS];
    #pragma unroll
    for (int m = 0; m < KCLS; ++m) cs[m] = clsLDS[m];
    float sii = cs[self];
    float psum = 0.f, psq = 0.f, pmin = 1e30f;
    #pragma unroll
    for (int m = 0; m < KCLS; ++m) {
        if (m != self) {
            psum += cs[m];
            psq  += cs[m] * cs[m];
            pmin  = fminf(pmin, cs[m]);
        }
    }
    const float p = (float)(KCLS - 1);            // 7
    const float mneg = (float)(NROWS - KCLS);     // 4088
    float nsum = S - psum - sii;
    float nsq  = SQ - psq - sii * sii;
    float pmean = psum / p;
    float pstd  = sqrtf(fmaxf(psq / p - pmean * pmean, 0.f));
    float nmean = nsum / mneg;
    float nstd  = sqrtf(fmaxf(nsq / mneg - nmean * nmean, 0.f));
    float inter  = 0.8f * (nstd * pmean + pstd * nmean) / (pstd + nstd) + 0.1f;
    float thresh = pmin - 0.05f;

    // ---- pass B: filter + softplus over this thread's 16 elems ----
    float cnt = 0.f, nls = 0.f;
    const int jb = t * 16;
    #pragma unroll
    for (int d = 0; d < 8; ++d) {
        float lo = __uint_as_float(w[d] << 16);
        float hi = __uint_as_float(w[d] & 0xffff0000u);
        int jl = jb + 2 * d;
        if (((jl >> 3) != rcls) && lo > thresh) {
            cnt += 1.f;
            nls += softplus_fast(40.f * (lo - inter));
        }
        if ((((jl + 1) >> 3) != rcls) && hi > thresh) {
            cnt += 1.f;
            nls += softplus_fast(40.f * (hi - inter));
        }
    }
    #pragma unroll
    for (int off = 32; off > 0; off >>= 1) {
        cnt += __shfl_down(cnt, off);
        nls += __shfl_down(nls, off);
    }
    __shared__ float sc[4], sn[4];
    if ((t & 63) == 0) { sc[t >> 6] = cnt; sn[t >> 6] = nls; }
    __syncthreads();
    if (t == 0) {
        float C = sc[0] + sc[1] + sc[2] + sc[3];
        float L = sn[0] + sn[1] + sn[2] + sn[3];
        int ci = (int)C;
        float pl = 0.f;
        #pragma unroll
        for (int m = 0; m < KCLS; ++m) {
            if (m != self) pl += softplus_fast(-10.f * (cs[m] - inter));
        }
        pl *= 0.2f / p;
        rowCnt[r]  = ci;
        rowPsum[r] = psum;
        rowNsum[r] = nsum;
        rowLoss[r] = (ci > 0) ? (pl + 0.05f * L / C) : 0.f;
    }
}

__global__ __launch_bounds__(256)
void finalize_kernel(const float* __restrict__ rowLoss,
                     const int* __restrict__ rowCnt,
                     const float* __restrict__ rowPsum,
                     const float* __restrict__ rowNsum,
                     float* __restrict__ out)
{
    const int t = threadIdx.x;
    float loss = 0.f, inv = 0.f, pd = 0.f, nd = 0.f;
    for (int r = t; r < NROWS; r += 256) {
        loss += rowLoss[r];
        inv  += (rowCnt[r] == 0) ? 1.f : 0.f;
        pd   += rowPsum[r];
        nd   += rowNsum[r];
    }
    #pragma unroll
    for (int off = 32; off > 0; off >>= 1) {
        loss += __shfl_down(loss, off);
        inv  += __shfl_down(inv, off);
        pd   += __shfl_down(pd, off);
        nd   += __shfl_down(nd, off);
    }
    __shared__ float sl[4], si[4], sp[4], sq[4];
    int w = t >> 6;
    if ((t & 63) == 0) { sl[w] = loss; si[w] = inv; sp[w] = pd; sq[w] = nd; }
    __syncthreads();
    if (t == 0) {
        float L = sl[0] + sl[1] + sl[2] + sl[3];
        float I = si[0] + si[1] + si[2] + si[3];
        float P = sp[0] + sp[1] + sp[2] + sp[3];
        float Nn = sq[0] + sq[1] + sq[2] + sq[3];
        out[0] = L / (float)NROWS;
        out[1] = I / (float)NROWS;
        out[2] = P / ((float)NROWS * (float)(KCLS - 1));
        out[3] = Nn / ((float)NROWS * (float)(NROWS - KCLS));
    }
}

extern "C" void kernel_launch(void* const* d_in, const int* in_sizes, int n_in,
                              void* d_out, int out_size, void* d_ws, size_t ws_size,
                              hipStream_t stream)
{
    const float* X = (const float*)d_in[0];

    float* ws      = (float*)d_ws;
    float* rowLoss = ws;                           // 4096
    float* rowPsum = ws + NROWS;                   // 4096
    float* rowNsum = ws + 2 * NROWS;               // 4096
    int*   rowCnt  = (int*)(ws + 3 * NROWS);       // 4096
    unsigned short* Xf   = (unsigned short*)(ws + 4 * NROWS);   // 2 MB
    unsigned short* simB = Xf + (size_t)NROWS * DIM;            // 4096*4128*2 B ~ 33.8 MB
    // total ws use: ~36 MB; no zero-init required (no atomics anywhere)

    convert_kernel<<<512, 256, 0, stream>>>(X, Xf);

    dim3 grid(32, 64);   // 2048 blocks, 4 waves each; 64-col j-slices
    gemm_kernel<<<grid, 256, 0, stream>>>(Xf, simB);

    sweep_kernel<<<NROWS, 256, 0, stream>>>(simB, rowLoss, rowCnt, rowPsum, rowNsum);

    finalize_kernel<<<1, 256, 0, stream>>>(rowLoss, rowCnt, rowPsum, rowNsum,
                                           (float*)d_out);
}

// Round 10
// 105.090 us; speedup vs baseline: 3.3420x; 1.0027x over previous
//
#include <hip/hip_runtime.h>
#include <math.h>

// MarginDevianceLoss: N=4096, D=256, K=8, targets = i/8.
// Outputs: [loss, prec, pos_d, neg_d] fp32.
//
// R10: NO sim materialization (R9's gemm+sweep round-tripped 68 MB; that was
// the real cost — pitch/triangle tweaks were noise). Two fused MFMA passes:
//   pass1: GEMM + sum/sumsq epilogue + diag classSim -> per-(row, jblock)
//          float4 partial stores (1 MB, no atomics).
//   stats: per-row reduce partials -> inter/thresh/posLoss/psum/nsum.
//   pass2: GEMM + hard-negative filter + softplus epilogue -> cnt/nls partials.
//   finalA: per-row partial reduce; finalB: 4096 -> 4 outputs.
// Xf fragment-major bf16 (coalesced 1-KB fragment loads). 6 dispatches.

#define NROWS 4096
#define DIM   256
#define KCLS  8
#define NJB   32     // j-blocks = partials per row

typedef __bf16 bf16x8 __attribute__((ext_vector_type(8)));
typedef float  f32x4  __attribute__((ext_vector_type(4)));

__device__ __forceinline__ float softplus_fast(float z) {
    float m = fmaxf(z, 0.f);
    float e = __builtin_exp2f(-fabsf(z) * 1.4426950408889634f);
    return m + 0.6931471805599453f * __builtin_log2f(1.f + e);
}

__device__ __forceinline__ unsigned int pack_bf2(float a, float b) {
    unsigned int ua = __float_as_uint(a);
    unsigned int ub = __float_as_uint(b);
    ua = (ua + 0x7FFFu + ((ua >> 16) & 1u)) >> 16;   // RNE
    ub = (ub + 0x7FFFu + ((ub >> 16) & 1u)) >> 16;
    return ua | (ub << 16);
}

// X (fp32 row-major) -> Xf (bf16 fragment-major):
// Xf[((tile*8 + kf)*64 + lane)*8 + e] = X[tile*16 + (lane&15)][kf*32 + (lane>>4)*8 + e]
__global__ __launch_bounds__(256)
void convert_kernel(const float* __restrict__ X, unsigned short* __restrict__ Xf)
{
    int v = blockIdx.x * 256 + threadIdx.x;    // 131072 fragment-slices of 16 B
    int tile = v >> 9;
    int kf   = (v >> 6) & 7;
    int lane = v & 63;
    int row  = tile * 16 + (lane & 15);
    int c4   = kf * 8 + (lane >> 4) * 2;       // col/4
    const float4* X4 = reinterpret_cast<const float4*>(X);
    float4 a = X4[row * 64 + c4];
    float4 b = X4[row * 64 + c4 + 1];
    uint4 o;
    o.x = pack_bf2(a.x, a.y);
    o.y = pack_bf2(a.z, a.w);
    o.z = pack_bf2(b.x, b.y);
    o.w = pack_bf2(b.z, b.w);
    reinterpret_cast<uint4*>(Xf)[v] = o;
}

// Grid (32,32). Block: 4 waves; wave w -> i-tiles {bx*8+w*2, +1} (A cached in
// regs, K=256). All waves sweep j-tiles [by*8,+8) (B frags shared -> L1).
// Epilogue: rowSum/rowSumSq accumulation; classSim capture on diag blocks.
// Quad shuffle-reduce -> float4 partial stores at part[by*4096 + i].
__global__ __launch_bounds__(256)
void gemm_stats_kernel(const unsigned short* __restrict__ Xf,
                       float* __restrict__ sumPart,
                       float* __restrict__ sqPart,
                       float* __restrict__ classSim)
{
    const int lane = threadIdx.x & 63;
    const int wave = threadIdx.x >> 6;
    const int quad = lane >> 4;
    const int n16  = lane & 15;
    const int it0  = blockIdx.x * 8 + wave * 2;
    const int i0   = it0 * 16;
    const int j0   = blockIdx.y * 128;
    const int jt0  = blockIdx.y * 8;
    const bool diag = (blockIdx.x == blockIdx.y);

    bf16x8 afrag[2][8];
    #pragma unroll
    for (int t = 0; t < 2; ++t) {
        const unsigned short* ap = Xf + ((size_t)(it0 + t) * 8) * 512 + lane * 8;
        #pragma unroll
        for (int kf = 0; kf < 8; ++kf)
            afrag[t][kf] = *reinterpret_cast<const bf16x8*>(ap + kf * 512);
    }

    float sI[2][4]  = {};
    float sqI[2][4] = {};

    bf16x8 bA[8], bB[8];
    auto loadB = [&](bf16x8* bf, int jt) {
        const unsigned short* bp = Xf + ((size_t)(jt0 + jt) * 8) * 512 + lane * 8;
        #pragma unroll
        for (int kf = 0; kf < 8; ++kf)
            bf[kf] = *reinterpret_cast<const bf16x8*>(bp + kf * 512);
    };
    auto tile = [&](const bf16x8* bf, int jt) {
        f32x4 ac[2] = {{0.f, 0.f, 0.f, 0.f}, {0.f, 0.f, 0.f, 0.f}};
        #pragma unroll
        for (int kf = 0; kf < 8; ++kf) {
            ac[0] = __builtin_amdgcn_mfma_f32_16x16x32_bf16(afrag[0][kf], bf[kf], ac[0], 0, 0, 0);
            ac[1] = __builtin_amdgcn_mfma_f32_16x16x32_bf16(afrag[1][kf], bf[kf], ac[1], 0, 0, 0);
        }
        #pragma unroll
        for (int t = 0; t < 2; ++t)
            #pragma unroll
            for (int r = 0; r < 4; ++r) {
                float s = ac[t][r];
                sI[t][r]  += s;
                sqI[t][r] += s * s;
            }
        if (diag) {                       // wave-uniform: 32/1024 blocks
            int j = j0 + jt * 16 + n16;
            #pragma unroll
            for (int t = 0; t < 2; ++t)
                #pragma unroll
                for (int r = 0; r < 4; ++r) {
                    int i = i0 + t * 16 + quad * 4 + r;
                    if (((i ^ j) >> 3) == 0)
                        classSim[i * KCLS + (j & 7)] = ac[t][r];
                }
        }
    };

    loadB(bA, 0);
    #pragma unroll 1
    for (int jp = 0; jp < 4; ++jp) {
        loadB(bB, 2 * jp + 1);
        tile(bA, 2 * jp);
        if (jp < 3) loadB(bA, 2 * jp + 2);
        tile(bB, 2 * jp + 1);
    }

    // reduce across the 16 lanes of each quad (same rows)
    #pragma unroll
    for (int t = 0; t < 2; ++t) {
        #pragma unroll
        for (int r = 0; r < 4; ++r) {
            #pragma unroll
            for (int m = 8; m >= 1; m >>= 1) {
                sI[t][r]  += __shfl_xor(sI[t][r], m);
                sqI[t][r] += __shfl_xor(sqI[t][r], m);
            }
        }
        if (n16 == 0) {
            int base = blockIdx.y * NROWS + i0 + t * 16 + quad * 4;
            float4 vs = {sI[t][0], sI[t][1], sI[t][2], sI[t][3]};
            float4 vq = {sqI[t][0], sqI[t][1], sqI[t][2], sqI[t][3]};
            *reinterpret_cast<float4*>(&sumPart[base]) = vs;
            *reinterpret_cast<float4*>(&sqPart[base])  = vq;
        }
    }
}

// One thread per row: reduce 32 partials, classSim -> inter/thresh/posLoss/
// psum/nsum.
__global__ __launch_bounds__(256)
void stats_kernel(const float* __restrict__ sumPart,
                  const float* __restrict__ sqPart,
                  const float* __restrict__ classSim,
                  float* __restrict__ interA,
                  float* __restrict__ threshA,
                  float* __restrict__ posLossA,
                  float* __restrict__ rowPsum,
                  float* __restrict__ rowNsum)
{
    const int i = blockIdx.x * 256 + threadIdx.x;
    const int self = i & 7;

    float S = 0.f, SQ = 0.f;
    #pragma unroll
    for (int b = 0; b < NJB; ++b) {
        S  += sumPart[b * NROWS + i];
        SQ += sqPart[b * NROWS + i];
    }

    float4 c0 = reinterpret_cast<const float4*>(classSim)[i * 2];
    float4 c1 = reinterpret_cast<const float4*>(classSim)[i * 2 + 1];
    float cs[KCLS] = {c0.x, c0.y, c0.z, c0.w, c1.x, c1.y, c1.z, c1.w};

    float sii = cs[self];
    float psum = 0.f, psq = 0.f, pmin = 1e30f;
    #pragma unroll
    for (int m = 0; m < KCLS; ++m) {
        if (m != self) {
            psum += cs[m];
            psq  += cs[m] * cs[m];
            pmin  = fminf(pmin, cs[m]);
        }
    }
    const float p = (float)(KCLS - 1);            // 7
    const float mneg = (float)(NROWS - KCLS);     // 4088
    float nsum = S - psum - sii;
    float nsq  = SQ - psq - sii * sii;
    float pmean = psum / p;
    float pstd  = sqrtf(fmaxf(psq / p - pmean * pmean, 0.f));
    float nmean = nsum / mneg;
    float nstd  = sqrtf(fmaxf(nsq / mneg - nmean * nmean, 0.f));
    float inter  = 0.8f * (nstd * pmean + pstd * nmean) / (pstd + nstd) + 0.1f;

    float pl = 0.f;
    #pragma unroll
    for (int m = 0; m < KCLS; ++m) {
        if (m != self) pl += softplus_fast(-10.f * (cs[m] - inter));
    }
    pl *= 0.2f / p;

    interA[i]   = inter;
    threshA[i]  = pmin - 0.05f;
    posLossA[i] = pl;
    rowPsum[i]  = psum;
    rowNsum[i]  = nsum;
}

// Same GEMM frame; epilogue = hard-negative filter + softplus.
// Quad shuffle-reduce -> float4 partial stores cnt/nls at part[by*4096 + i].
__global__ __launch_bounds__(256)
void gemm_filter_kernel(const unsigned short* __restrict__ Xf,
                        const float* __restrict__ interA,
                        const float* __restrict__ threshA,
                        float* __restrict__ cntPart,
                        float* __restrict__ nlsPart)
{
    const int lane = threadIdx.x & 63;
    const int wave = threadIdx.x >> 6;
    const int quad = lane >> 4;
    const int n16  = lane & 15;
    const int it0  = blockIdx.x * 8 + wave * 2;
    const int i0   = it0 * 16;
    const int j0   = blockIdx.y * 128;
    const int jt0  = blockIdx.y * 8;

    bf16x8 afrag[2][8];
    #pragma unroll
    for (int t = 0; t < 2; ++t) {
        const unsigned short* ap = Xf + ((size_t)(it0 + t) * 8) * 512 + lane * 8;
        #pragma unroll
        for (int kf = 0; kf < 8; ++kf)
            afrag[t][kf] = *reinterpret_cast<const bf16x8*>(ap + kf * 512);
    }

    float interR[2][4], threshR[2][4];
    int   icls[2];
    #pragma unroll
    for (int t = 0; t < 2; ++t) {
        icls[t] = (i0 + t * 16 + quad * 4) >> 3;   // r-independent (4 rows share class)
        #pragma unroll
        for (int r = 0; r < 4; ++r) {
            int i = i0 + t * 16 + quad * 4 + r;
            interR[t][r]  = interA[i];
            threshR[t][r] = threshA[i];
        }
    }

    float cnt[2][4] = {};
    float nls[2][4] = {};

    bf16x8 bA[8], bB[8];
    auto loadB = [&](bf16x8* bf, int jt) {
        const unsigned short* bp = Xf + ((size_t)(jt0 + jt) * 8) * 512 + lane * 8;
        #pragma unroll
        for (int kf = 0; kf < 8; ++kf)
            bf[kf] = *reinterpret_cast<const bf16x8*>(bp + kf * 512);
    };
    auto tile = [&](const bf16x8* bf, int jt) {
        f32x4 ac[2] = {{0.f, 0.f, 0.f, 0.f}, {0.f, 0.f, 0.f, 0.f}};
        #pragma unroll
        for (int kf = 0; kf < 8; ++kf) {
            ac[0] = __builtin_amdgcn_mfma_f32_16x16x32_bf16(afrag[0][kf], bf[kf], ac[0], 0, 0, 0);
            ac[1] = __builtin_amdgcn_mfma_f32_16x16x32_bf16(afrag[1][kf], bf[kf], ac[1], 0, 0, 0);
        }
        const int jcls = (j0 + jt * 16 + n16) >> 3;
        #pragma unroll
        for (int t = 0; t < 2; ++t) {
            const bool neg = (icls[t] != jcls);
            #pragma unroll
            for (int r = 0; r < 4; ++r) {
                float s = ac[t][r];
                if (neg && s > threshR[t][r]) {
                    cnt[t][r] += 1.f;
                    nls[t][r] += softplus_fast(40.f * (s - interR[t][r]));
                }
            }
        }
    };

    loadB(bA, 0);
    #pragma unroll 1
    for (int jp = 0; jp < 4; ++jp) {
        loadB(bB, 2 * jp + 1);
        tile(bA, 2 * jp);
        if (jp < 3) loadB(bA, 2 * jp + 2);
        tile(bB, 2 * jp + 1);
    }

    #pragma unroll
    for (int t = 0; t < 2; ++t) {
        #pragma unroll
        for (int r = 0; r < 4; ++r) {
            #pragma unroll
            for (int m = 8; m >= 1; m >>= 1) {
                cnt[t][r] += __shfl_xor(cnt[t][r], m);
                nls[t][r] += __shfl_xor(nls[t][r], m);
            }
        }
        if (n16 == 0) {
            int base = blockIdx.y * NROWS + i0 + t * 16 + quad * 4;
            float4 vc = {cnt[t][0], cnt[t][1], cnt[t][2], cnt[t][3]};
            float4 vn = {nls[t][0], nls[t][1], nls[t][2], nls[t][3]};
            *reinterpret_cast<float4*>(&cntPart[base]) = vc;
            *reinterpret_cast<float4*>(&nlsPart[base]) = vn;
        }
    }
}

// One thread per row: reduce cnt/nls partials -> rowLoss, rowInv.
__global__ __launch_bounds__(256)
void finalA_kernel(const float* __restrict__ cntPart,
                   const float* __restrict__ nlsPart,
                   const float* __restrict__ posLossA,
                   float* __restrict__ rowLoss,
                   float* __restrict__ rowInv)
{
    const int i = blockIdx.x * 256 + threadIdx.x;
    float c = 0.f, n = 0.f;
    #pragma unroll
    for (int b = 0; b < NJB; ++b) {
        c += cntPart[b * NROWS + i];
        n += nlsPart[b * NROWS + i];
    }
    rowLoss[i] = (c > 0.f) ? (posLossA[i] + 0.05f * n / c) : 0.f;
    rowInv[i]  = (c > 0.f) ? 0.f : 1.f;
}

__global__ __launch_bounds__(256)
void finalB_kernel(const float* __restrict__ rowLoss,
                   const float* __restrict__ rowInv,
                   const float* __restrict__ rowPsum,
                   const float* __restrict__ rowNsum,
                   float* __restrict__ out)
{
    const int t = threadIdx.x;
    float loss = 0.f, inv = 0.f, pd = 0.f, nd = 0.f;
    for (int r = t; r < NROWS; r += 256) {
        loss += rowLoss[r];
        inv  += rowInv[r];
        pd   += rowPsum[r];
        nd   += rowNsum[r];
    }
    #pragma unroll
    for (int off = 32; off > 0; off >>= 1) {
        loss += __shfl_down(loss, off);
        inv  += __shfl_down(inv, off);
        pd   += __shfl_down(pd, off);
        nd   += __shfl_down(nd, off);
    }
    __shared__ float sl[4], si[4], sp[4], sq[4];
    int w = t >> 6;
    if ((t & 63) == 0) { sl[w] = loss; si[w] = inv; sp[w] = pd; sq[w] = nd; }
    __syncthreads();
    if (t == 0) {
        float L = sl[0] + sl[1] + sl[2] + sl[3];
        float I = si[0] + si[1] + si[2] + si[3];
        float P = sp[0] + sp[1] + sp[2] + sp[3];
        float Nn = sq[0] + sq[1] + sq[2] + sq[3];
        out[0] = L / (float)NROWS;
        out[1] = I / (float)NROWS;
        out[2] = P / ((float)NROWS * (float)(KCLS - 1));
        out[3] = Nn / ((float)NROWS * (float)(NROWS - KCLS));
    }
}

extern "C" void kernel_launch(void* const* d_in, const int* in_sizes, int n_in,
                              void* d_out, int out_size, void* d_ws, size_t ws_size,
                              hipStream_t stream)
{
    const float* X = (const float*)d_in[0];

    float* ws       = (float*)d_ws;
    float* sumPart  = ws;                                   // 32*4096
    float* sqPart   = sumPart + NJB * NROWS;                // 32*4096
    float* cntPart  = sqPart  + NJB * NROWS;                // 32*4096
    float* nlsPart  = cntPart + NJB * NROWS;                // 32*4096
    float* classSim = nlsPart + NJB * NROWS;                // 4096*8
    float* interA   = classSim + NROWS * KCLS;              // 4096
    float* threshA  = interA  + NROWS;
    float* posLossA = threshA + NROWS;
    float* rowPsum  = posLossA + NROWS;
    float* rowNsum  = rowPsum + NROWS;
    float* rowLoss  = rowNsum + NROWS;
    float* rowInv   = rowLoss + NROWS;
    unsigned short* Xf = (unsigned short*)(rowInv + NROWS); // 2 MB
    // total ws use: ~4.5 MB; everything fully written before read (no init)

    convert_kernel<<<512, 256, 0, stream>>>(X, Xf);

    dim3 grid(32, 32);
    gemm_stats_kernel<<<grid, 256, 0, stream>>>(Xf, sumPart, sqPart, classSim);

    stats_kernel<<<NROWS / 256, 256, 0, stream>>>(sumPart, sqPart, classSim,
                                                  interA, threshA, posLossA,
                                                  rowPsum, rowNsum);

    gemm_filter_kernel<<<grid, 256, 0, stream>>>(Xf, interA, threshA,
                                                 cntPart, nlsPart);

    finalA_kernel<<<NROWS / 256, 256, 0, stream>>>(cntPart, nlsPart, posLossA,
                                                   rowLoss, rowInv);

    finalB_kernel<<<1, 256, 0, stream>>>(rowLoss, rowInv, rowPsum, rowNsum,
                                         (float*)d_out);
}

// Round 11
// 101.090 us; speedup vs baseline: 3.4743x; 1.0396x over previous
//
#include <hip/hip_runtime.h>
#include <math.h>

// MarginDevianceLoss: N=4096, D=256, K=8, targets = i/8.
// Outputs: [loss, prec, pos_d, neg_d] fp32.
//
// R11: R10 structure (no sim materialization, two fused MFMA passes) with the
// GEMM B-path restructured m97-style:
//  - B fragments staged to LDS once per block via global_load_lds (width 16),
//    double-buffered, 1 barrier/j-tile. Kills the 4x-redundant per-wave global
//    loads that made R4-R10 GEMMs latency-bound (MfmaUtil 7%, VALUBusy 26%).
//  - A register-cached per wave (K=256), fragment-major Xf as before.
//  - Branchless filter epilogue with poly-softplus (1 transcendental).
// 6 dispatches, no atomics.

#define NROWS 4096
#define DIM   256
#define KCLS  8
#define NJB   32     // j-blocks = partials per row

typedef __bf16 bf16x8 __attribute__((ext_vector_type(8)));
typedef float  f32x4  __attribute__((ext_vector_type(4)));

// log(1+exp(z)) = max(z,0) + ln2 * log2(1 + exp2(-|z|*log2e)).
// log2(1+u), u in (0,1], approximated by quartic (abs err <= ~4e-4):
__device__ __forceinline__ float softplus_poly(float z) {
    float u = __builtin_exp2f(-1.4426950408889634f * __builtin_fabsf(z));
    float p = u * (1.4426950f + u * (-0.6949650f + u * (0.3454302f + u * -0.0931600f)));
    return fmaf(p, 0.6931471805599453f, fmaxf(z, 0.f));
}

__device__ __forceinline__ unsigned int pack_bf2(float a, float b) {
    unsigned int ua = __float_as_uint(a);
    unsigned int ub = __float_as_uint(b);
    ua = (ua + 0x7FFFu + ((ua >> 16) & 1u)) >> 16;   // RNE
    ub = (ub + 0x7FFFu + ((ub >> 16) & 1u)) >> 16;
    return ua | (ub << 16);
}

__device__ __forceinline__ void glds16(const unsigned short* g, unsigned short* l) {
    // HW semantics: each lane reads 16 B at its own g; LDS dest = uniform l + lane*16.
    __builtin_amdgcn_global_load_lds(
        (const __attribute__((address_space(1))) void*)g,
        (__attribute__((address_space(3))) void*)l, 16, 0, 0);
}

// X (fp32 row-major) -> Xf (bf16 fragment-major):
// Xf[((tile*8 + kf)*64 + lane)*8 + e] = X[tile*16 + (lane&15)][kf*32 + (lane>>4)*8 + e]
__global__ __launch_bounds__(256)
void convert_kernel(const float* __restrict__ X, unsigned short* __restrict__ Xf)
{
    int v = blockIdx.x * 256 + threadIdx.x;    // 131072 fragment-slices of 16 B
    int tile = v >> 9;
    int kf   = (v >> 6) & 7;
    int lane = v & 63;
    int row  = tile * 16 + (lane & 15);
    int c4   = kf * 8 + (lane >> 4) * 2;       // col/4
    const float4* X4 = reinterpret_cast<const float4*>(X);
    float4 a = X4[row * 64 + c4];
    float4 b = X4[row * 64 + c4 + 1];
    uint4 o;
    o.x = pack_bf2(a.x, a.y);
    o.y = pack_bf2(a.z, a.w);
    o.z = pack_bf2(b.x, b.y);
    o.w = pack_bf2(b.z, b.w);
    reinterpret_cast<uint4*>(Xf)[v] = o;
}

// Grid (32,32). Block: 4 waves; wave w -> i-tiles {bx*8+w*2, +1} (A cached in
// regs, K=256). All waves sweep j-tiles [by*8,+8); B staged via LDS
// (global_load_lds, double-buffered, 2 frags/wave/tile).
// PASS 1 (STATS=1): sum/sumsq epilogue + diag classSim -> float4 partials.
// PASS 2 (STATS=0): branchless filter + poly-softplus -> cnt/nls partials.
template<int STATS>
__global__ __launch_bounds__(256)
void gemm_pass_kernel(const unsigned short* __restrict__ Xf,
                      const float* __restrict__ interA,
                      const float* __restrict__ threshA,
                      float* __restrict__ outPartA,   // sumPart  / cntPart
                      float* __restrict__ outPartB,   // sqPart   / nlsPart
                      float* __restrict__ classSim)
{
    __shared__ __align__(16) unsigned short Bs[2][8][512];   // 2 x 8 KB

    const int lane = threadIdx.x & 63;
    const int wave = threadIdx.x >> 6;
    const int quad = lane >> 4;
    const int n16  = lane & 15;
    const int it0  = blockIdx.x * 8 + wave * 2;
    const int i0   = it0 * 16;
    const int j0   = blockIdx.y * 128;
    const int jt0  = blockIdx.y * 8;
    const bool diag = (blockIdx.x == blockIdx.y);

    // A fragments: 2 i-tiles x 8 k-frags, coalesced 1-KB global loads
    bf16x8 afrag[2][8];
    #pragma unroll
    for (int t = 0; t < 2; ++t) {
        const unsigned short* ap = Xf + ((size_t)(it0 + t) * 8) * 512 + lane * 8;
        #pragma unroll
        for (int kf = 0; kf < 8; ++kf)
            afrag[t][kf] = *reinterpret_cast<const bf16x8*>(ap + kf * 512);
    }

    float accA[2][4] = {};       // sI / cnt
    float accB[2][4] = {};       // sqI / nls
    float c40[2][4], threshR[2][4];
    int   icls[2];
    if constexpr (!STATS) {
        #pragma unroll
        for (int t = 0; t < 2; ++t) {
            icls[t] = (i0 + t * 16 + quad * 4) >> 3;   // rows quad*4..+3 share class
            #pragma unroll
            for (int r = 0; r < 4; ++r) {
                int i = i0 + t * 16 + quad * 4 + r;
                c40[t][r]     = -40.f * interA[i];
                threshR[t][r] = threshA[i];
            }
        }
    }

    // stage B frags for j-tile jt into buffer buf: wave w loads frags 2w,2w+1
    auto stage = [&](int buf, int jt) {
        const unsigned short* src =
            Xf + ((size_t)(jt0 + jt) * 8 + wave * 2) * 512 + lane * 8;
        glds16(src,       &Bs[buf][wave * 2][0]);
        glds16(src + 512, &Bs[buf][wave * 2 + 1][0]);
    };

    stage(0, 0);
    __syncthreads();

    int buf = 0;
    #pragma unroll 1
    for (int jt = 0; jt < 8; ++jt) {
        if (jt < 7) stage(buf ^ 1, jt + 1);

        bf16x8 bfr[8];
        #pragma unroll
        for (int kf = 0; kf < 8; ++kf)
            bfr[kf] = *reinterpret_cast<const bf16x8*>(&Bs[buf][kf][lane * 8]);

        f32x4 ac[2] = {{0.f, 0.f, 0.f, 0.f}, {0.f, 0.f, 0.f, 0.f}};
        #pragma unroll
        for (int kf = 0; kf < 8; ++kf) {
            ac[0] = __builtin_amdgcn_mfma_f32_16x16x32_bf16(afrag[0][kf], bfr[kf], ac[0], 0, 0, 0);
            ac[1] = __builtin_amdgcn_mfma_f32_16x16x32_bf16(afrag[1][kf], bfr[kf], ac[1], 0, 0, 0);
        }

        if constexpr (STATS) {
            #pragma unroll
            for (int t = 0; t < 2; ++t)
                #pragma unroll
                for (int r = 0; r < 4; ++r) {
                    float s = ac[t][r];
                    accA[t][r] += s;
                    accB[t][r] = fmaf(s, s, accB[t][r]);
                }
            if (diag) {                    // wave-uniform: 32/1024 blocks
                int j = j0 + jt * 16 + n16;
                #pragma unroll
                for (int t = 0; t < 2; ++t)
                    #pragma unroll
                    for (int r = 0; r < 4; ++r) {
                        int i = i0 + t * 16 + quad * 4 + r;
                        if (((i ^ j) >> 3) == 0)
                            classSim[i * KCLS + (j & 7)] = ac[t][r];
                    }
            }
        } else {
            const int jcls = (j0 + jt * 16 + n16) >> 3;
            #pragma unroll
            for (int t = 0; t < 2; ++t) {
                const bool neg = (icls[t] != jcls);
                #pragma unroll
                for (int r = 0; r < 4; ++r) {
                    float s  = ac[t][r];
                    float sp = softplus_poly(fmaf(40.f, s, c40[t][r]));
                    float m  = (neg && s > threshR[t][r]) ? 1.f : 0.f;
                    accA[t][r] += m;
                    accB[t][r] = fmaf(m, sp, accB[t][r]);
                }
            }
        }

        __syncthreads();    // drains glds for jt+1; frees buf for jt+2
        buf ^= 1;
    }

    // reduce across the 16 lanes of each quad (same rows) -> float4 partials
    #pragma unroll
    for (int t = 0; t < 2; ++t) {
        #pragma unroll
        for (int r = 0; r < 4; ++r) {
            #pragma unroll
            for (int m = 8; m >= 1; m >>= 1) {
                accA[t][r] += __shfl_xor(accA[t][r], m);
                accB[t][r] += __shfl_xor(accB[t][r], m);
            }
        }
        if (n16 == 0) {
            int base = blockIdx.y * NROWS + i0 + t * 16 + quad * 4;
            float4 va = {accA[t][0], accA[t][1], accA[t][2], accA[t][3]};
            float4 vb = {accB[t][0], accB[t][1], accB[t][2], accB[t][3]};
            *reinterpret_cast<float4*>(&outPartA[base]) = va;
            *reinterpret_cast<float4*>(&outPartB[base]) = vb;
        }
    }
}

// One thread per row: reduce 32 partials + classSim -> inter/thresh/posLoss/
// psum/nsum.
__global__ __launch_bounds__(256)
void stats_kernel(const float* __restrict__ sumPart,
                  const float* __restrict__ sqPart,
                  const float* __restrict__ classSim,
                  float* __restrict__ interA,
                  float* __restrict__ threshA,
                  float* __restrict__ posLossA,
                  float* __restrict__ rowPsum,
                  float* __restrict__ rowNsum)
{
    const int i = blockIdx.x * 256 + threadIdx.x;
    const int self = i & 7;

    float S = 0.f, SQ = 0.f;
    #pragma unroll
    for (int b = 0; b < NJB; ++b) {
        S  += sumPart[b * NROWS + i];
        SQ += sqPart[b * NROWS + i];
    }

    float4 c0 = reinterpret_cast<const float4*>(classSim)[i * 2];
    float4 c1 = reinterpret_cast<const float4*>(classSim)[i * 2 + 1];
    float cs[KCLS] = {c0.x, c0.y, c0.z, c0.w, c1.x, c1.y, c1.z, c1.w};

    float sii = cs[self];
    float psum = 0.f, psq = 0.f, pmin = 1e30f;
    #pragma unroll
    for (int m = 0; m < KCLS; ++m) {
        if (m != self) {
            psum += cs[m];
            psq  += cs[m] * cs[m];
            pmin  = fminf(pmin, cs[m]);
        }
    }
    const float p = (float)(KCLS - 1);            // 7
    const float mneg = (float)(NROWS - KCLS);     // 4088
    float nsum = S - psum - sii;
    float nsq  = SQ - psq - sii * sii;
    float pmean = psum / p;
    float pstd  = sqrtf(fmaxf(psq / p - pmean * pmean, 0.f));
    float nmean = nsum / mneg;
    float nstd  = sqrtf(fmaxf(nsq / mneg - nmean * nmean, 0.f));
    float inter  = 0.8f * (nstd * pmean + pstd * nmean) / (pstd + nstd) + 0.1f;

    float pl = 0.f;
    #pragma unroll
    for (int m = 0; m < KCLS; ++m) {
        if (m != self) pl += softplus_poly(-10.f * (cs[m] - inter));
    }
    pl *= 0.2f / p;

    interA[i]   = inter;
    threshA[i]  = pmin - 0.05f;
    posLossA[i] = pl;
    rowPsum[i]  = psum;
    rowNsum[i]  = nsum;
}

// One thread per row: reduce cnt/nls partials -> rowLoss, rowInv.
__global__ __launch_bounds__(256)
void finalA_kernel(const float* __restrict__ cntPart,
                   const float* __restrict__ nlsPart,
                   const float* __restrict__ posLossA,
                   float* __restrict__ rowLoss,
                   float* __restrict__ rowInv)
{
    const int i = blockIdx.x * 256 + threadIdx.x;
    float c = 0.f, n = 0.f;
    #pragma unroll
    for (int b = 0; b < NJB; ++b) {
        c += cntPart[b * NROWS + i];
        n += nlsPart[b * NROWS + i];
    }
    rowLoss[i] = (c > 0.f) ? (posLossA[i] + 0.05f * n / c) : 0.f;
    rowInv[i]  = (c > 0.f) ? 0.f : 1.f;
}

__global__ __launch_bounds__(256)
void finalB_kernel(const float* __restrict__ rowLoss,
                   const float* __restrict__ rowInv,
                   const float* __restrict__ rowPsum,
                   const float* __restrict__ rowNsum,
                   float* __restrict__ out)
{
    const int t = threadIdx.x;
    float loss = 0.f, inv = 0.f, pd = 0.f, nd = 0.f;
    for (int r = t; r < NROWS; r += 256) {
        loss += rowLoss[r];
        inv  += rowInv[r];
        pd   += rowPsum[r];
        nd   += rowNsum[r];
    }
    #pragma unroll
    for (int off = 32; off > 0; off >>= 1) {
        loss += __shfl_down(loss, off);
        inv  += __shfl_down(inv, off);
        pd   += __shfl_down(pd, off);
        nd   += __shfl_down(nd, off);
    }
    __shared__ float sl[4], si[4], sp[4], sq[4];
    int w = t >> 6;
    if ((t & 63) == 0) { sl[w] = loss; si[w] = inv; sp[w] = pd; sq[w] = nd; }
    __syncthreads();
    if (t == 0) {
        float L = sl[0] + sl[1] + sl[2] + sl[3];
        float I = si[0] + si[1] + si[2] + si[3];
        float P = sp[0] + sp[1] + sp[2] + sp[3];
        float Nn = sq[0] + sq[1] + sq[2] + sq[3];
        out[0] = L / (float)NROWS;
        out[1] = I / (float)NROWS;
        out[2] = P / ((float)NROWS * (float)(KCLS - 1));
        out[3] = Nn / ((float)NROWS * (float)(NROWS - KCLS));
    }
}

extern "C" void kernel_launch(void* const* d_in, const int* in_sizes, int n_in,
                              void* d_out, int out_size, void* d_ws, size_t ws_size,
                              hipStream_t stream)
{
    const float* X = (const float*)d_in[0];

    float* ws       = (float*)d_ws;
    float* sumPart  = ws;                                   // 32*4096
    float* sqPart   = sumPart + NJB * NROWS;                // 32*4096
    float* cntPart  = sqPart  + NJB * NROWS;                // 32*4096
    float* nlsPart  = cntPart + NJB * NROWS;                // 32*4096
    float* classSim = nlsPart + NJB * NROWS;                // 4096*8
    float* interA   = classSim + NROWS * KCLS;              // 4096
    float* threshA  = interA  + NROWS;
    float* posLossA = threshA + NROWS;
    float* rowPsum  = posLossA + NROWS;
    float* rowNsum  = rowPsum + NROWS;
    float* rowLoss  = rowNsum + NROWS;
    float* rowInv   = rowLoss + NROWS;
    unsigned short* Xf = (unsigned short*)(rowInv + NROWS); // 2 MB
    // total ws use: ~4.5 MB; everything fully written before read (no init)

    convert_kernel<<<512, 256, 0, stream>>>(X, Xf);

    dim3 grid(32, 32);
    gemm_pass_kernel<1><<<grid, 256, 0, stream>>>(Xf, nullptr, nullptr,
                                                  sumPart, sqPart, classSim);

    stats_kernel<<<NROWS / 256, 256, 0, stream>>>(sumPart, sqPart, classSim,
                                                  interA, threshA, posLossA,
                                                  rowPsum, rowNsum);

    gemm_pass_kernel<0><<<grid, 256, 0, stream>>>(Xf, interA, threshA,
                                                  cntPart, nlsPart, nullptr);

    finalA_kernel<<<NROWS / 256, 256, 0, stream>>>(cntPart, nlsPart, posLossA,
                                                   rowLoss, rowInv);

    finalB_kernel<<<1, 256, 0, stream>>>(rowLoss, rowInv, rowPsum, rowNsum,
                                         (float*)d_out);
}